// Round 15
// baseline (108.002 us; speedup 1.0000x reference)
//
#include <hip/hip_runtime.h>
#include <stdint.h>

typedef __attribute__((ext_vector_type(4))) int int32x4;

#define PK_TILE_U32 131072   // one 128-row packed tile = 512 KB = 131072 u32
#define PK_TILE_B   524288

// ---------------------------------------------------------------------------
// sign_pack2: f32 -> i8 (+1/-1) for BOTH matrices in one launch (grid.y picks
// the matrix). Blocked k-major layout:
//   [tile = row/128][chunk = k/16][row % 128][16 bytes]
// Each 64-k slice of a 128-row tile is one LINEAR 8 KB block.
// ---------------------------------------------------------------------------
__global__ __launch_bounds__(256) void sign_pack2(const float* __restrict__ x,
                                                  const float* __restrict__ w,
                                                  uint32_t* __restrict__ xp,
                                                  uint32_t* __restrict__ wp) {
    const float* in = blockIdx.y ? w : x;
    uint32_t* outp  = blockIdx.y ? wp : xp;
    const int lane = threadIdx.x & 63;
    const int wave = (blockIdx.x * blockDim.x + threadIdx.x) >> 6;
    const int nw   = (gridDim.x * blockDim.x) >> 6;
    for (int it = wave; it < 4096 * 16; it += nw) {
        const int row = it >> 4;
        const int col = ((it & 15) << 8) + lane * 4;
        float4 v = *(const float4*)(in + (size_t)row * 4096 + col);
        uint32_t wd = (v.x > 0.f ? 1u : 0xFFu)
                    | ((v.y > 0.f ? 1u : 0xFFu) << 8)
                    | ((v.z > 0.f ? 1u : 0xFFu) << 16)
                    | ((v.w > 0.f ? 1u : 0xFFu) << 24);
        const int tile = row >> 7, rl = row & 127;
        const int chunk = col >> 4;          // k/16
        const int word  = (col >> 2) & 3;    // u32 within 16B slot
        outp[(size_t)tile * PK_TILE_U32 + chunk * 512 + rl * 4 + word] = wd;
    }
}

// ---------------------------------------------------------------------------
// i8 MFMA GEMM v7 — faithful 8-phase template port (T3+T4+T5 as a unit).
// R13 (coarse, syncthreads) = 70 us; R14 (coarse, counted) = 77 us — per
// m196/m218 coarse splits don't pay; the fine phase interleave is the lever.
// Geometry (R13-verified exact): 256x256 tile, 512 thr = 8 waves (2Mx4N),
// wave tile 128x64, acc[8][4] AGPR-native.
// Half-tile = 64-k slice = 32 KB (A 16K @0: [rt2][chunk4][row128][16B],
// B 16K @16384 same). Ring of 4 slots = 128 KB LDS, staged 3 ahead with
// 4 x global_load_lds(8 KB linear region) per slot.
// Per slot, 2 phases:
//   STAGE(slot+3); vmcnt(12); barrier  [slot landed for ALL waves]
//   {8 ds_read a0-3,b0-3; lgkmcnt(0); setprio(1); 16 MFMA; setprio(0); bar}
//   {4 ds_read a4-7;      lgkmcnt(0); setprio(1); 16 MFMA; setprio(0); bar}
// vmcnt NEVER drains to 0 in the loop (tail 8/4/0). End barrier doubles as
// the pre-STAGE barrier of the next group (stage targets the slot consumed
// in the previous group — reads sealed by that barrier).
// Per group: MFMA 1306 cyc/CU vs LDS ~600-900 -> MFMA-bound by construction.
// Frag reads 256B-contiguous per 16 lanes (0 conflicts measured).
// Grid 256 = 1 block/CU, bijective XCD swizzle.
// ---------------------------------------------------------------------------
__global__ __launch_bounds__(512) void i8_gemm7(const uint32_t* __restrict__ xp,
                                                const uint32_t* __restrict__ wp,
                                                float* __restrict__ out) {
    __shared__ uint4 ldsv[8192];   // 128 KB = 4 slots x 32 KB
    uint8_t* lds = (uint8_t*)ldsv;

    const int tid  = threadIdx.x;
    const int lane = tid & 63;
    const int wv   = tid >> 6;           // 0..7
    const int wr   = wv >> 2;            // row half
    const int wc   = wv & 3;             // col quarter

    // bijective XCD swizzle (256 % 8 == 0)
    int lid = blockIdx.x;
    lid = (lid & 7) * 32 + (lid >> 3);
    const int brow = lid >> 4, bcol = lid & 15;

    const uint8_t* gA = (const uint8_t*)(xp + (size_t)(brow * 2) * PK_TILE_U32) + tid * 16;
    const uint8_t* gB = (const uint8_t*)(wp + (size_t)(bcol * 2) * PK_TILE_U32) + tid * 16;
    const int wvo = wv * 1024;

#define GL(src, doff) __builtin_amdgcn_global_load_lds( \
        (const __attribute__((address_space(1))) uint32_t*)(src), \
        (__attribute__((address_space(3))) uint32_t*)(lds + (doff) + wvo), 16, 0, 0)

    // one half-tile (k-slice ks, 64 k): 4 linear 8 KB regions
#define STAGE4(ks, boff) do {                                   \
        GL(gA + (size_t)(ks) * 8192,             (boff) +     0); \
        GL(gA + PK_TILE_B + (size_t)(ks) * 8192, (boff) +  8192); \
        GL(gB + (size_t)(ks) * 8192,             (boff) + 16384); \
        GL(gB + PK_TILE_B + (size_t)(ks) * 8192, (boff) + 24576); \
    } while (0)

    int32x4 acc[8][4];
#pragma unroll
    for (int m = 0; m < 8; ++m)
#pragma unroll
        for (int n = 0; n < 4; ++n) acc[m][n] = (int32x4){0, 0, 0, 0};

    // frag bases within a slot (R13-verified):
    const int paBase = wr * 8192 + (lane >> 4) * 2048 + (lane & 15) * 16;
    const int pbBase = 16384 + (wc >> 1) * 8192 + (lane >> 4) * 2048
                     + ((wc & 1) * 64 + (lane & 15)) * 16;

    // prologue: stage slots 0,1,2 (12 loads in flight)
    STAGE4(0, 0);
    STAGE4(1, 32768);
    STAGE4(2, 65536);

#pragma unroll 1
    for (int g = 0; g < 64; ++g) {
        const int bo = (g & 3) * 32768;
        if (g + 3 < 64) STAGE4(g + 3, ((g + 3) & 3) * 32768);

        // T4 counted wait: slot g's 4 loads done; 3 slots (12 loads) in flight
        if (g < 61)       asm volatile("s_waitcnt vmcnt(12)" ::: "memory");
        else if (g == 61) asm volatile("s_waitcnt vmcnt(8)"  ::: "memory");
        else if (g == 62) asm volatile("s_waitcnt vmcnt(4)"  ::: "memory");
        else              asm volatile("s_waitcnt vmcnt(0)"  ::: "memory");
        __builtin_amdgcn_s_barrier();            // slot landed for ALL waves
        __builtin_amdgcn_sched_barrier(0);

        // ---- phase A: m0-3 ------------------------------------------------
        int32x4 a[4], b[4];
#pragma unroll
        for (int n = 0; n < 4; ++n) b[n] = *(const int32x4*)(lds + bo + pbBase + n * 256);
#pragma unroll
        for (int m = 0; m < 4; ++m) a[m] = *(const int32x4*)(lds + bo + paBase + m * 256);
        asm volatile("s_waitcnt lgkmcnt(0)" ::: "memory");
        __builtin_amdgcn_sched_barrier(0);
        __builtin_amdgcn_s_setprio(1);
#pragma unroll
        for (int m = 0; m < 4; ++m)
#pragma unroll
            for (int n = 0; n < 4; ++n)
                acc[m][n] = __builtin_amdgcn_mfma_i32_16x16x64_i8(a[m], b[n], acc[m][n], 0, 0, 0);
        __builtin_amdgcn_s_setprio(0);
        __builtin_amdgcn_s_barrier();

        // ---- phase B: m4-7 ------------------------------------------------
#pragma unroll
        for (int m = 0; m < 4; ++m) a[m] = *(const int32x4*)(lds + bo + paBase + (m + 4) * 256);
        asm volatile("s_waitcnt lgkmcnt(0)" ::: "memory");
        __builtin_amdgcn_sched_barrier(0);
        __builtin_amdgcn_s_setprio(1);
#pragma unroll
        for (int m = 0; m < 4; ++m)
#pragma unroll
            for (int n = 0; n < 4; ++n)
                acc[m + 4][n] = __builtin_amdgcn_mfma_i32_16x16x64_i8(a[m], b[n], acc[m + 4][n], 0, 0, 0);
        __builtin_amdgcn_s_setprio(0);
        __builtin_amdgcn_s_barrier();            // doubles as pre-STAGE barrier of g+1
    }

    // epilogue: i32 -> f32 exact. C/D: col = lane&15, row = (lane>>4)*4 + reg
    const int orow = brow * 256 + wr * 128 + (lane >> 4) * 4;
    const int ocol = bcol * 256 + wc * 64 + (lane & 15);
#pragma unroll
    for (int m = 0; m < 8; ++m)
#pragma unroll
        for (int reg = 0; reg < 4; ++reg) {
            const size_t rb = (size_t)(orow + m * 16 + reg) * 4096 + ocol;
#pragma unroll
            for (int n = 0; n < 4; ++n)
                out[rb + n * 16] = (float)acc[m][n][reg];
        }
#undef STAGE4
#undef GL
}

// ======================= fallback (R8 binary path) =========================
__global__ __launch_bounds__(256) void binarize64(const float* __restrict__ in,
                                                  unsigned long long* __restrict__ out,
                                                  int n64) {
    const int tid  = blockIdx.x * blockDim.x + threadIdx.x;
    const int lane = threadIdx.x & 63;
    const int wave = tid >> 6;
    const int nwav = (gridDim.x * blockDim.x) >> 6;
    for (int w = wave; w < n64; w += nwav) {
        float v = in[(size_t)w * 64 + lane];
        unsigned long long m = __ballot(v > 0.0f);
        if (lane == 0) out[w] = m;
    }
}

static __device__ __forceinline__ void pacc4(uint32_t& acc, const uint4& a, const uint4& b) {
    uint32_t t0, t1, t2, t3;
    asm("v_xor_b32 %1, %5, %9\n\t"
        "v_xor_b32 %2, %6, %10\n\t"
        "v_xor_b32 %3, %7, %11\n\t"
        "v_xor_b32 %4, %8, %12\n\t"
        "v_bcnt_u32_b32 %0, %1, %0\n\t"
        "v_bcnt_u32_b32 %0, %2, %0\n\t"
        "v_bcnt_u32_b32 %0, %3, %0\n\t"
        "v_bcnt_u32_b32 %0, %4, %0"
        : "+v"(acc), "=&v"(t0), "=&v"(t1), "=&v"(t2), "=&v"(t3)
        : "v"(a.x), "v"(a.y), "v"(a.z), "v"(a.w),
          "v"(b.x), "v"(b.y), "v"(b.z), "v"(b.w));
}

__global__ __launch_bounds__(256, 2) void xnor_gemm(const uint32_t* __restrict__ xb,
                                                    const uint32_t* __restrict__ wb,
                                                    float* __restrict__ out) {
    __shared__ uint4 lA[128 * 8];
    __shared__ uint4 lB[64 * 8];
    const int tid  = threadIdx.x;
    const int brow = blockIdx.y, bcol = blockIdx.x;
    const int tx = tid & 15, ty = tid >> 4;
    const uint4* gA = (const uint4*)xb + (size_t)(brow * 128) * 32;
    const uint4* gB = (const uint4*)wb + (size_t)(bcol * 64) * 32;
    const int sr = tid >> 3, scw = tid & 7;
    uint32_t acc[8][4];
#pragma unroll
    for (int r = 0; r < 8; ++r)
#pragma unroll
        for (int c = 0; c < 4; ++c) acc[r][c] = 0;
    const uint4* pa = lA + ty * 64;
    const uint4* pb = lB + tx * 32;
    const int ka = ty & 7, kb = tx >> 1;
    for (int ck = 0; ck < 4; ++ck) {
        if (ck) __syncthreads();
#pragma unroll
        for (int k = 0; k < 4; ++k) {
            const int r = sr + k * 32;
            lA[r * 8 + (scw ^ ((r >> 3) & 7))] = gA[(size_t)r * 32 + ck * 8 + scw];
        }
#pragma unroll
        for (int k = 0; k < 2; ++k) {
            const int r = sr + k * 32;
            lB[r * 8 + (scw ^ ((r >> 3) & 7))] = gB[(size_t)r * 32 + ck * 8 + scw];
        }
        __syncthreads();
#pragma unroll 1
        for (int j = 0; j < 8; ++j) {
            const uint4* paj = pa + (j ^ ka);
            const uint4* pbj = pb + (j ^ kb);
            uint4 a[8], b[4];
#pragma unroll
            for (int r = 0; r < 8; ++r) a[r] = paj[r * 8];
#pragma unroll
            for (int c = 0; c < 4; ++c) b[c] = pbj[c * 8];
#pragma unroll
            for (int r = 0; r < 8; ++r)
#pragma unroll
                for (int c = 0; c < 4; ++c) pacc4(acc[r][c], a[r], b[c]);
        }
    }
    const int gcol = bcol * 64 + tx * 4;
#pragma unroll
    for (int r = 0; r < 8; ++r) {
        const size_t grow = (size_t)(brow * 128 + ty * 8 + r);
        float4 o;
        o.x = (float)(4096 - 2 * (int)acc[r][0]);
        o.y = (float)(4096 - 2 * (int)acc[r][1]);
        o.z = (float)(4096 - 2 * (int)acc[r][2]);
        o.w = (float)(4096 - 2 * (int)acc[r][3]);
        *(float4*)(out + grow * 4096 + gcol) = o;
    }
}

extern "C" void kernel_launch(void* const* d_in, const int* in_sizes, int n_in,
                              void* d_out, int out_size, void* d_ws, size_t ws_size,
                              hipStream_t stream) {
    const float* x = (const float*)d_in[0];   // [4096, 4096]
    const float* W = (const float*)d_in[1];   // [4096, 4096] (out, in)
    float* out = (float*)d_out;               // [4096, 4096] f32

    if (ws_size >= 2u * 16777216u) {
        // MFMA i8 path: needs 32 MB workspace
        uint32_t* xp = (uint32_t*)d_ws;                 // 16 MB packed x
        uint32_t* wpk = xp + (size_t)4194304;           // 16 MB packed W
        sign_pack2<<<dim3(2048, 2), 256, 0, stream>>>(x, W, xp, wpk);
        i8_gemm7<<<256, 512, 0, stream>>>(xp, wpk, out);
    } else {
        // fallback: binary xor-popcount path (needs 4 MB)
        uint32_t* xb = (uint32_t*)d_ws;
        uint32_t* wb = xb + (size_t)4096 * 128;
        const int n64 = 4096 * 4096 / 64;
        binarize64<<<2048, 256, 0, stream>>>(x, (unsigned long long*)xb, n64);
        binarize64<<<2048, 256, 0, stream>>>(W, (unsigned long long*)wb, n64);
        dim3 grid(64, 32);
        xnor_gemm<<<grid, 256, 0, stream>>>(xb, wb, out);
    }
}

// Round 16
// 102.739 us; speedup vs baseline: 1.0512x; 1.0512x over previous
//
#include <hip/hip_runtime.h>
#include <stdint.h>

typedef __attribute__((ext_vector_type(4))) int int32x4;

#define PK_TILE_U32 131072   // one 128-row packed tile = 512 KB = 131072 u32
#define PK_TILE_B   524288

// ---------------------------------------------------------------------------
// sign_pack2: f32 -> i8 (+1/-1), blocked k-major layout:
//   [tile = row/128][chunk = k/16][row % 128][16 bytes]
// Each 64-k slice of a 128-row tile is one LINEAR 8 KB block.
// ---------------------------------------------------------------------------
__global__ __launch_bounds__(256) void sign_pack2(const float* __restrict__ x,
                                                  const float* __restrict__ w,
                                                  uint32_t* __restrict__ xp,
                                                  uint32_t* __restrict__ wp) {
    const float* in = blockIdx.y ? w : x;
    uint32_t* outp  = blockIdx.y ? wp : xp;
    const int lane = threadIdx.x & 63;
    const int wave = (blockIdx.x * blockDim.x + threadIdx.x) >> 6;
    const int nw   = (gridDim.x * blockDim.x) >> 6;
    for (int it = wave; it < 4096 * 16; it += nw) {
        const int row = it >> 4;
        const int col = ((it & 15) << 8) + lane * 4;
        float4 v = *(const float4*)(in + (size_t)row * 4096 + col);
        uint32_t wd = (v.x > 0.f ? 1u : 0xFFu)
                    | ((v.y > 0.f ? 1u : 0xFFu) << 8)
                    | ((v.z > 0.f ? 1u : 0xFFu) << 16)
                    | ((v.w > 0.f ? 1u : 0xFFu) << 24);
        const int tile = row >> 7, rl = row & 127;
        const int chunk = col >> 4;          // k/16
        const int word  = (col >> 2) & 3;    // u32 within 16B slot
        outp[(size_t)tile * PK_TILE_U32 + chunk * 512 + rl * 4 + word] = wd;
    }
}

// ---------------------------------------------------------------------------
// i8 MFMA GEMM v8 — exact template phase ordering (reads BEFORE barrier,
// lgkmcnt AFTER). R15 issued reads after the barrier with a naked lgkm(0):
// all 8 waves bunch reads -> LDS queue drain exposed, MFMA tail exposed —
// measured as fully-summed pipes (5250 cyc/K-tile = MFMA 2611 + LDS ~1900 +
// slop across R13/R14/R15). Template ordering hides read latency + queue
// drain under barrier skew and interleaves each phase's reads/stage with the
// previous phase's in-flight MFMA.
// Geometry (R13/R15-verified exact): 256x256 tile, 512 thr = 8 waves (2Mx4N),
// wave tile 128x64, acc[8][4] AGPR-native. Slot = 64-k slice = 32 KB
// (A 16K: [rt2][chunk4][row128][16B]; B 16K @+16384). Ring 4 slots = 128 KB.
// Stage lead = 2 slots: restage target sealed two barriers back (airtight);
// per slot phase A stages half (2 GL), phase B the other half + vmcnt(4)
// (= slot g+1's 4 loads done, g+2's 4 stay in flight; never drains to 0).
// Per phase: {reads; stage; [vmcnt]; sched_bar; s_barrier; lgkm(0);
//            sched_bar; setprio1; 16 MFMA; setprio0}.
// Grid 256 = 1 block/CU, bijective XCD swizzle.
// ---------------------------------------------------------------------------
__global__ __launch_bounds__(512) void i8_gemm8(const uint32_t* __restrict__ xp,
                                                const uint32_t* __restrict__ wp,
                                                float* __restrict__ out) {
    __shared__ uint4 ldsv[8192];   // 128 KB = 4 slots x 32 KB
    uint8_t* lds = (uint8_t*)ldsv;

    const int tid  = threadIdx.x;
    const int lane = tid & 63;
    const int wv   = tid >> 6;           // 0..7
    const int wr   = wv >> 2;            // row half
    const int wc   = wv & 3;             // col quarter

    int lid = blockIdx.x;                // bijective XCD swizzle (256%8==0)
    lid = (lid & 7) * 32 + (lid >> 3);
    const int brow = lid >> 4, bcol = lid & 15;

    const uint8_t* gA = (const uint8_t*)(xp + (size_t)(brow * 2) * PK_TILE_U32) + tid * 16;
    const uint8_t* gB = (const uint8_t*)(wp + (size_t)(bcol * 2) * PK_TILE_U32) + tid * 16;

#define GL(src, doff) __builtin_amdgcn_global_load_lds( \
        (const __attribute__((address_space(1))) uint32_t*)(src), \
        (__attribute__((address_space(3))) uint32_t*)(lds + (doff) + wv * 1024), 16, 0, 0)

    // A half of slot s (2 row-tiles, 16 KB)
#define STAGE_A(s, boff) do {                                     \
        GL(gA + (size_t)(s) * 8192,             (boff) +     0);  \
        GL(gA + PK_TILE_B + (size_t)(s) * 8192, (boff) +  8192);  \
    } while (0)
    // B half of slot s (16 KB)
#define STAGE_B(s, boff) do {                                     \
        GL(gB + (size_t)(s) * 8192,             (boff) + 16384);  \
        GL(gB + PK_TILE_B + (size_t)(s) * 8192, (boff) + 24576);  \
    } while (0)

    int32x4 acc[8][4];
#pragma unroll
    for (int m = 0; m < 8; ++m)
#pragma unroll
        for (int n = 0; n < 4; ++n) acc[m][n] = (int32x4){0, 0, 0, 0};

    const int paBase = wr * 8192 + (lane >> 4) * 2048 + (lane & 15) * 16;
    const int pbBase = 16384 + (wc >> 1) * 8192 + (lane >> 4) * 2048
                     + ((wc & 1) * 64 + (lane & 15)) * 16;

    // prologue: stage slots 0 and 1 fully (8 loads in flight)
    STAGE_A(0, 0);     STAGE_B(0, 0);
    STAGE_A(1, 32768); STAGE_B(1, 32768);
    // slot 0 must be resident before first reads
    asm volatile("s_waitcnt vmcnt(4)" ::: "memory");
    __builtin_amdgcn_s_barrier();

#pragma unroll 1
    for (int g = 0; g < 64; ++g) {
        const int bo = (g & 3) * 32768;
        const int so = ((g + 2) & 3) * 32768;

        // ---- phase A ------------------------------------------------------
        int32x4 a[4], b[4];
#pragma unroll
        for (int n = 0; n < 4; ++n) b[n] = *(const int32x4*)(lds + bo + pbBase + n * 256);
#pragma unroll
        for (int m = 0; m < 4; ++m) a[m] = *(const int32x4*)(lds + bo + paBase + m * 256);
        if (g + 2 < 64) STAGE_A(g + 2, so);
        __builtin_amdgcn_sched_barrier(0);     // pin reads/stage before barrier
        __builtin_amdgcn_s_barrier();
        asm volatile("s_waitcnt lgkmcnt(0)" ::: "memory");
        __builtin_amdgcn_sched_barrier(0);     // rule 18: no MFMA hoist above lgkm
        __builtin_amdgcn_s_setprio(1);
#pragma unroll
        for (int m = 0; m < 4; ++m)
#pragma unroll
            for (int n = 0; n < 4; ++n)
                acc[m][n] = __builtin_amdgcn_mfma_i32_16x16x64_i8(a[m], b[n], acc[m][n], 0, 0, 0);
        __builtin_amdgcn_s_setprio(0);

        // ---- phase B ------------------------------------------------------
#pragma unroll
        for (int m = 0; m < 4; ++m) a[m] = *(const int32x4*)(lds + bo + paBase + (m + 4) * 256);
        if (g + 2 < 64) STAGE_B(g + 2, so);
        // counted wait: slot g+1's 4 loads done; slot g+2's 4 stay in flight
        if (g < 62)       asm volatile("s_waitcnt vmcnt(4)" ::: "memory");
        else if (g == 62) asm volatile("s_waitcnt vmcnt(0)" ::: "memory");
        __builtin_amdgcn_sched_barrier(0);
        __builtin_amdgcn_s_barrier();
        asm volatile("s_waitcnt lgkmcnt(0)" ::: "memory");
        __builtin_amdgcn_sched_barrier(0);
        __builtin_amdgcn_s_setprio(1);
#pragma unroll
        for (int m = 0; m < 4; ++m)
#pragma unroll
            for (int n = 0; n < 4; ++n)
                acc[m + 4][n] = __builtin_amdgcn_mfma_i32_16x16x64_i8(a[m], b[n], acc[m + 4][n], 0, 0, 0);
        __builtin_amdgcn_s_setprio(0);
    }

    // epilogue: i32 -> f32 exact. C/D: col = lane&15, row = (lane>>4)*4 + reg
    const int orow = brow * 256 + wr * 128 + (lane >> 4) * 4;
    const int ocol = bcol * 256 + wc * 64 + (lane & 15);
#pragma unroll
    for (int m = 0; m < 8; ++m)
#pragma unroll
        for (int reg = 0; reg < 4; ++reg) {
            const size_t rb = (size_t)(orow + m * 16 + reg) * 4096 + ocol;
#pragma unroll
            for (int n = 0; n < 4; ++n)
                out[rb + n * 16] = (float)acc[m][n][reg];
        }
#undef STAGE_A
#undef STAGE_B
#undef GL
}

// ======================= fallback (R8 binary path) =========================
__global__ __launch_bounds__(256) void binarize64(const float* __restrict__ in,
                                                  unsigned long long* __restrict__ out,
                                                  int n64) {
    const int tid  = blockIdx.x * blockDim.x + threadIdx.x;
    const int lane = threadIdx.x & 63;
    const int wave = tid >> 6;
    const int nwav = (gridDim.x * blockDim.x) >> 6;
    for (int w = wave; w < n64; w += nwav) {
        float v = in[(size_t)w * 64 + lane];
        unsigned long long m = __ballot(v > 0.0f);
        if (lane == 0) out[w] = m;
    }
}

static __device__ __forceinline__ void pacc4(uint32_t& acc, const uint4& a, const uint4& b) {
    uint32_t t0, t1, t2, t3;
    asm("v_xor_b32 %1, %5, %9\n\t"
        "v_xor_b32 %2, %6, %10\n\t"
        "v_xor_b32 %3, %7, %11\n\t"
        "v_xor_b32 %4, %8, %12\n\t"
        "v_bcnt_u32_b32 %0, %1, %0\n\t"
        "v_bcnt_u32_b32 %0, %2, %0\n\t"
        "v_bcnt_u32_b32 %0, %3, %0\n\t"
        "v_bcnt_u32_b32 %0, %4, %0"
        : "+v"(acc), "=&v"(t0), "=&v"(t1), "=&v"(t2), "=&v"(t3)
        : "v"(a.x), "v"(a.y), "v"(a.z), "v"(a.w),
          "v"(b.x), "v"(b.y), "v"(b.z), "v"(b.w));
}

__global__ __launch_bounds__(256, 2) void xnor_gemm(const uint32_t* __restrict__ xb,
                                                    const uint32_t* __restrict__ wb,
                                                    float* __restrict__ out) {
    __shared__ uint4 lA[128 * 8];
    __shared__ uint4 lB[64 * 8];
    const int tid  = threadIdx.x;
    const int brow = blockIdx.y, bcol = blockIdx.x;
    const int tx = tid & 15, ty = tid >> 4;
    const uint4* gA = (const uint4*)xb + (size_t)(brow * 128) * 32;
    const uint4* gB = (const uint4*)wb + (size_t)(bcol * 64) * 32;
    const int sr = tid >> 3, scw = tid & 7;
    uint32_t acc[8][4];
#pragma unroll
    for (int r = 0; r < 8; ++r)
#pragma unroll
        for (int c = 0; c < 4; ++c) acc[r][c] = 0;
    const uint4* pa = lA + ty * 64;
    const uint4* pb = lB + tx * 32;
    const int ka = ty & 7, kb = tx >> 1;
    for (int ck = 0; ck < 4; ++ck) {
        if (ck) __syncthreads();
#pragma unroll
        for (int k = 0; k < 4; ++k) {
            const int r = sr + k * 32;
            lA[r * 8 + (scw ^ ((r >> 3) & 7))] = gA[(size_t)r * 32 + ck * 8 + scw];
        }
#pragma unroll
        for (int k = 0; k < 2; ++k) {
            const int r = sr + k * 32;
            lB[r * 8 + (scw ^ ((r >> 3) & 7))] = gB[(size_t)r * 32 + ck * 8 + scw];
        }
        __syncthreads();
#pragma unroll 1
        for (int j = 0; j < 8; ++j) {
            const uint4* paj = pa + (j ^ ka);
            const uint4* pbj = pb + (j ^ kb);
            uint4 a[8], b[4];
#pragma unroll
            for (int r = 0; r < 8; ++r) a[r] = paj[r * 8];
#pragma unroll
            for (int c = 0; c < 4; ++c) b[c] = pbj[c * 8];
#pragma unroll
            for (int r = 0; r < 8; ++r)
#pragma unroll
                for (int c = 0; c < 4; ++c) pacc4(acc[r][c], a[r], b[c]);
        }
    }
    const int gcol = bcol * 64 + tx * 4;
#pragma unroll
    for (int r = 0; r < 8; ++r) {
        const size_t grow = (size_t)(brow * 128 + ty * 8 + r);
        float4 o;
        o.x = (float)(4096 - 2 * (int)acc[r][0]);
        o.y = (float)(4096 - 2 * (int)acc[r][1]);
        o.z = (float)(4096 - 2 * (int)acc[r][2]);
        o.w = (float)(4096 - 2 * (int)acc[r][3]);
        *(float4*)(out + grow * 4096 + gcol) = o;
    }
}

extern "C" void kernel_launch(void* const* d_in, const int* in_sizes, int n_in,
                              void* d_out, int out_size, void* d_ws, size_t ws_size,
                              hipStream_t stream) {
    const float* x = (const float*)d_in[0];   // [4096, 4096]
    const float* W = (const float*)d_in[1];   // [4096, 4096] (out, in)
    float* out = (float*)d_out;               // [4096, 4096] f32

    if (ws_size >= 2u * 16777216u) {
        uint32_t* xp = (uint32_t*)d_ws;                 // 16 MB packed x
        uint32_t* wpk = xp + (size_t)4194304;           // 16 MB packed W
        sign_pack2<<<dim3(2048, 2), 256, 0, stream>>>(x, W, xp, wpk);
        i8_gemm8<<<256, 512, 0, stream>>>(xp, wpk, out);
    } else {
        uint32_t* xb = (uint32_t*)d_ws;
        uint32_t* wb = xb + (size_t)4096 * 128;
        const int n64 = 4096 * 4096 / 64;
        binarize64<<<2048, 256, 0, stream>>>(x, (unsigned long long*)xb, n64);
        binarize64<<<2048, 256, 0, stream>>>(W, (unsigned long long*)wb, n64);
        dim3 grid(64, 32);
        xnor_gemm<<<grid, 256, 0, stream>>>(xb, wb, out);
    }
}